// Round 4
// baseline (1221.823 us; speedup 1.0000x reference)
//
#include <hip/hip_runtime.h>
#include <hip/hip_bf16.h>
#include <math.h>

typedef unsigned short u16;
typedef __attribute__((ext_vector_type(8))) short bf16x8;
typedef __attribute__((ext_vector_type(4))) float f32x4;

#define B_    2048
#define V_    4096
#define L_    10
#define H_    512
#define E_    256
#define META_ 15
#define H4_   2048
#define KT_   1536                 // tripled K
#define NT_   48                   // KT_/32 k-tiles
#define EOS_  0
#define INIT_LEN_ (L_ + 1)

// ---- output layout (flat f32, reference return order) ----
constexpr size_t OUT_SL  = (size_t)B_ * (L_ + 1) * V_;
constexpr size_t OUT_ENT = OUT_SL + B_;
constexpr size_t OUT_EMB = OUT_ENT + 1;
constexpr size_t OUT_SP  = OUT_EMB + (size_t)B_ * L_ * E_;

// ---- workspace layout ----
constexpr size_t WS_E2G     = 0;                              // [V,4H] f32
constexpr size_t WS_LOGITS  = WS_E2G    + (size_t)V_ * H4_;   // [B,V] f32
constexpr size_t WS_G       = WS_LOGITS + (size_t)B_ * V_;    // [B,4H] f32
constexpr size_t WS_C       = WS_G      + (size_t)B_ * H4_;   // [B,H] f32
constexpr size_t WS_F32_END = WS_C      + (size_t)B_ * H_;
constexpr size_t U_B6       = 0;                              // [6144*1536] u16 tile-major
constexpr size_t U_HP       = U_B6 + (size_t)6144 * KT_;      // [B,1536] u16 row-major
constexpr size_t U_END      = U_HP + (size_t)B_ * KT_;

__device__ __forceinline__ u16 f2bf(float f) {
    union { __hip_bfloat16 b; u16 u; } cv; cv.b = __float2bfloat16(f); return cv.u;
}
__device__ __forceinline__ float bf2f(u16 u) {
    union { u16 u; __hip_bfloat16 b; } cv; cv.u = u; return __bfloat162float(cv.b);
}
__device__ __forceinline__ void gld16(const u16* g, void* l) {
    __builtin_amdgcn_global_load_lds(
        (const __attribute__((address_space(1))) unsigned int*)g,
        (__attribute__((address_space(3))) unsigned int*)l, 16, 0, 0);
}

// B6 tile-major addressing: panel p = col>>8 (48 k-tiles of 8192 elems each),
// within tile: slot-major [s][row][8]
__device__ __forceinline__ size_t b6_addr(int col, int k) {
    const int p = col >> 8, row = col & 255, kt = k >> 5, s = (k >> 3) & 3, e = k & 7;
    return (size_t)(p * NT_ + kt) * 8192 + s * 2048 + row * 8 + e;
}

// ---------------------------------------------------------------------------
// Pipelined 256x256 bf16 NT GEMM over K=1536 (counted vmcnt, 8 waves 2Mx4N).
// A row-major [2048][1536]; B6 tile-major.  col0<4H -> G raw; else LOGITS+bias.
// ---------------------------------------------------------------------------
__global__ __launch_bounds__(512, 1)
void gemm8(const u16* __restrict__ Ag, const u16* __restrict__ B6,
           float* __restrict__ G, float* __restrict__ LOG,
           const float* __restrict__ bias, int xoff)
{
    __shared__ u16 As[2][8192];   // [dbuf][slot-major 256x32]
    __shared__ u16 Bs[2][8192];
    const int tid  = threadIdx.x;
    const int lane = tid & 63;
    const int wave = tid >> 6;
    const int wr = wave >> 2, wc = wave & 3;     // 2M x 4N
    const int fr = lane & 15, kq = lane >> 4;

    // bijective XCD-chunked swizzle, column-clustered (gridDim.y == 8)
    const int nwg = gridDim.x * gridDim.y;
    const int bid = blockIdx.y * gridDim.x + blockIdx.x;
    const int w   = (bid & 7) * (nwg >> 3) + (bid >> 3);
    const int colb = (w >> 3) + xoff;
    const int row0 = (w & 7) * 256;
    const int col0 = colb * 256;

    // staging source pointers (per-thread)
    const u16* Asrc = Ag + (size_t)(row0 + (tid & 255)) * KT_ + (tid >> 8) * 8;
    const u16* Bsrc = B6 + (size_t)colb * (NT_ * 8192) + tid * 8;
    const int dst0 = tid * 8;

    // frag read bases (element offsets within a 8192-elem tile)
    const int abase = kq * 2048 + (wr * 128 + fr) * 8;
    const int bbase = kq * 2048 + (wc * 64 + fr) * 8;

    f32x4 acc[8][4] = {};
    bf16x8 aF[8], bF[4], aN[8], bN[4];

#define STAGE(buf, kt) do {                                    \
    gld16(Asrc + (kt) * 32,        &As[buf][dst0]);            \
    gld16(Asrc + (kt) * 32 + 16,   &As[buf][dst0 + 4096]);     \
    gld16(Bsrc + (kt) * 8192,        &Bs[buf][dst0]);          \
    gld16(Bsrc + (kt) * 8192 + 4096, &Bs[buf][dst0 + 4096]);   \
  } while (0)

    // prologue: stage tiles 0,1; wait tile0; read its frags
    STAGE(0, 0);
    STAGE(1, 1);
    asm volatile("s_waitcnt vmcnt(4)\ns_barrier" ::: "memory");
    {
        const u16* ap = &As[0][abase];
        const u16* bp = &Bs[0][bbase];
#pragma unroll
        for (int m = 0; m < 8; ++m) aF[m] = *(const bf16x8*)(ap + m * 128);
#pragma unroll
        for (int n = 0; n < 4; ++n) bF[n] = *(const bf16x8*)(bp + n * 128);
    }

#define BODY(T, AF, BF, AN, BN) do {                                          \
    const int cur = (T) & 1;                                                  \
    __builtin_amdgcn_s_setprio(1);                                            \
    _Pragma("unroll")                                                         \
    for (int m = 0; m < 8; ++m) {                                             \
      acc[m][0] = __builtin_amdgcn_mfma_f32_16x16x32_bf16(AF[m], BF[0], acc[m][0], 0, 0, 0); \
      acc[m][1] = __builtin_amdgcn_mfma_f32_16x16x32_bf16(AF[m], BF[1], acc[m][1], 0, 0, 0); \
    }                                                                         \
    __builtin_amdgcn_s_setprio(0);                                            \
    asm volatile("s_waitcnt lgkmcnt(0)\ns_barrier" ::: "memory");             \
    { int t2 = (T) + 2; if (t2 >= NT_) t2 = (T);                              \
      STAGE(cur, t2); }                                                       \
    __builtin_amdgcn_s_setprio(1);                                            \
    _Pragma("unroll")                                                         \
    for (int m = 0; m < 8; ++m)                                               \
      acc[m][2] = __builtin_amdgcn_mfma_f32_16x16x32_bf16(AF[m], BF[2], acc[m][2], 0, 0, 0); \
    __builtin_amdgcn_s_setprio(0);                                            \
    asm volatile("s_waitcnt vmcnt(4)\ns_barrier" ::: "memory");               \
    { const u16* ap = &As[cur ^ 1][abase];                                    \
      const u16* bp = &Bs[cur ^ 1][bbase];                                    \
      _Pragma("unroll")                                                       \
      for (int m = 0; m < 8; ++m) AN[m] = *(const bf16x8*)(ap + m * 128);     \
      _Pragma("unroll")                                                       \
      for (int n = 0; n < 4; ++n) BN[n] = *(const bf16x8*)(bp + n * 128); }   \
    __builtin_amdgcn_s_setprio(1);                                            \
    _Pragma("unroll")                                                         \
    for (int m = 0; m < 8; ++m)                                               \
      acc[m][3] = __builtin_amdgcn_mfma_f32_16x16x32_bf16(AF[m], BF[3], acc[m][3], 0, 0, 0); \
    __builtin_amdgcn_s_setprio(0);                                            \
  } while (0)

    for (int t = 0; t < NT_; t += 2) {
        BODY(t,     aF, bF, aN, bN);
        BODY(t + 1, aN, bN, aF, bF);
    }
#undef BODY
#undef STAGE

    // epilogue: whole 256-col panel is either G (panels 0-7) or LOGITS
    const bool isG = (col0 < H4_);
    float* Cb   = isG ? G : LOG;
    const int ldc  = isG ? H4_ : V_;
    const int cadj = isG ? 0 : H4_;
    const int cbase = col0 - cadj + wc * 64 + fr;
#pragma unroll
    for (int m = 0; m < 8; ++m) {
#pragma unroll
        for (int r = 0; r < 4; ++r) {
            const int grow = row0 + wr * 128 + m * 16 + kq * 4 + r;
            float* cp = Cb + (size_t)grow * ldc + cbase;
#pragma unroll
            for (int n = 0; n < 4; ++n) {
                float v = acc[m][n][r];
                if (!isG) v += bias[cbase + n * 16];
                cp[n * 16] = v;
            }
        }
    }
}

// ---------------------------------------------------------------------------
// repack W_hh [2048][512] f32 -> B6 panels 0-7 (hi|hi|lo over K)
__global__ __launch_bounds__(256)
void repack_whh(const float* __restrict__ W_hh, u16* __restrict__ B6)
{
    const int c0 = blockIdx.x * 32, k0 = blockIdx.y * 64;
    const int cc = threadIdx.x & 31, kg = threadIdx.x >> 5;
    const int col = c0 + cc;
#pragma unroll
    for (int e = 0; e < 8; ++e) {
        const int kp = k0 + kg * 8 + e;               // 0..511
        const float v = W_hh[(size_t)col * H_ + kp];
        const u16 h = f2bf(v);
        const u16 l = f2bf(v - bf2f(h));
        B6[b6_addr(col, kp)]          = h;
        B6[b6_addr(col, 512 + kp)]    = h;
        B6[b6_addr(col, 1024 + kp)]   = l;
    }
}

// repack W_out [512][4096] f32 (transposed) -> B6 panels 8-23
__global__ __launch_bounds__(256)
void repack_wout(const float* __restrict__ W_out, u16* __restrict__ B6)
{
    __shared__ float t[64][33];
    const int c0 = blockIdx.x * 32, k0 = blockIdx.y * 64;
    const int x = threadIdx.x & 31, y = threadIdx.x >> 5;   // 32 x 8
    for (int yy = y; yy < 64; yy += 8)
        t[yy][x] = W_out[(size_t)(k0 + yy) * V_ + c0 + x];
    __syncthreads();
    const int cc = threadIdx.x & 31, kg = threadIdx.x >> 5;
    const int col = 2048 + c0 + cc;
#pragma unroll
    for (int e = 0; e < 8; ++e) {
        const int kp = k0 + kg * 8 + e;
        const float v = t[kp - k0][cc];
        const u16 h = f2bf(v);
        const u16 l = f2bf(v - bf2f(h));
        B6[b6_addr(col, kp)]        = h;
        B6[b6_addr(col, 512 + kp)]  = h;
        B6[b6_addr(col, 1024 + kp)] = l;
    }
}

// ---------------------------------------------------------------------------
// exact-style old MFMA GEMM kept for the one-time E2G build (EPI 0 only)
template <int EPI>
__global__ __launch_bounds__(256)
void gemm3(const u16* __restrict__ Ah, const u16* __restrict__ Al,
           const u16* __restrict__ Bh, const u16* __restrict__ Bl,
           float* __restrict__ C0, float* __restrict__ C1, int K,
           const float* __restrict__ bias0, const float* __restrict__ bias1,
           int xoff)
{
    __shared__ u16 As[2][128][32];
    __shared__ u16 Bs[2][128][32];
    const int tid  = threadIdx.x;
    const int lane = tid & 63;
    const int wave = tid >> 6;
    const int wm = wave >> 1, wn = wave & 1;
    const int nwg  = gridDim.x * gridDim.y;
    const int bid  = blockIdx.y * gridDim.x + blockIdx.x;
    const int w    = (bid & 7) * (nwg >> 3) + (bid >> 3);
    const int colb = w / gridDim.y + xoff;
    const int rowb = w % gridDim.y;
    const int col0 = colb * 128;
    const int row0 = rowb * 128;

    const int srow = tid >> 2;
    const int scol = (tid & 3) * 8;
    const size_t aoff = (size_t)(row0 + srow) * K + scol;
    const size_t boff = (size_t)(col0 + srow) * K + scol;
    const size_t skip = (size_t)64 * K;

    u16* lA0 = &As[0][0][0];
    u16* lA1 = &As[1][0][0];
    u16* lB0 = &Bs[0][0][0];
    u16* lB1 = &Bs[1][0][0];
    const int d0 = tid * 8;
    const int d1 = d0 + 2048;

    f32x4 acc[4][4] = {};
    const int fr = lane & 15;
    const int kq = lane >> 4;

    for (int k0 = 0; k0 < K; k0 += 32) {
        __syncthreads();
        gld16(Ah + aoff + k0,        lA0 + d0);
        gld16(Ah + aoff + k0 + skip, lA0 + d1);
        gld16(Al + aoff + k0,        lA1 + d0);
        gld16(Al + aoff + k0 + skip, lA1 + d1);
        gld16(Bh + boff + k0,        lB0 + d0);
        gld16(Bh + boff + k0 + skip, lB0 + d1);
        gld16(Bl + boff + k0,        lB1 + d0);
        gld16(Bl + boff + k0 + skip, lB1 + d1);
        __syncthreads();

        bf16x8 ah[4], al[4], bh[4], bl[4];
#pragma unroll
        for (int i = 0; i < 4; ++i) {
            ah[i] = *(const bf16x8*)&As[0][wm * 64 + i * 16 + fr][kq * 8];
            al[i] = *(const bf16x8*)&As[1][wm * 64 + i * 16 + fr][kq * 8];
            bh[i] = *(const bf16x8*)&Bs[0][wn * 64 + i * 16 + fr][kq * 8];
            bl[i] = *(const bf16x8*)&Bs[1][wn * 64 + i * 16 + fr][kq * 8];
        }
#pragma unroll
        for (int mi = 0; mi < 4; ++mi)
#pragma unroll
            for (int ni = 0; ni < 4; ++ni) {
                acc[mi][ni] = __builtin_amdgcn_mfma_f32_16x16x32_bf16(ah[mi], bh[ni], acc[mi][ni], 0, 0, 0);
                acc[mi][ni] = __builtin_amdgcn_mfma_f32_16x16x32_bf16(ah[mi], bl[ni], acc[mi][ni], 0, 0, 0);
                acc[mi][ni] = __builtin_amdgcn_mfma_f32_16x16x32_bf16(al[mi], bh[ni], acc[mi][ni], 0, 0, 0);
            }
    }

    const int cc0 = col0 + wn * 64 + fr;
#pragma unroll
    for (int mi = 0; mi < 4; ++mi) {
#pragma unroll
        for (int r = 0; r < 4; ++r) {
            const int grow = row0 + wm * 64 + mi * 16 + kq * 4 + r;
            float* cp = C0 + (size_t)grow * H4_ + cc0;
#pragma unroll
            for (int ni = 0; ni < 4; ++ni)
                cp[ni * 16] = acc[mi][ni][r] + bias0[cc0 + ni * 16] + bias1[cc0 + ni * 16];
        }
    }
}

// ---------------------------------------------------------------------------
// elementwise f32 -> bf16 hi/lo split (emb, W_ih for E2G build)
__global__ __launch_bounds__(256)
void split_mat(const float* __restrict__ X, u16* __restrict__ hi,
               u16* __restrict__ lo)
{
    const int i = blockIdx.x * 256 + threadIdx.x;
    float4 v = ((const float4*)X)[i];
    const u16 h0 = f2bf(v.x), h1 = f2bf(v.y), h2 = f2bf(v.z), h3 = f2bf(v.w);
    ((ushort4*)hi)[i] = make_ushort4(h0, h1, h2, h3);
    ((ushort4*)lo)[i] = make_ushort4(f2bf(v.x - bf2f(h0)), f2bf(v.y - bf2f(h1)),
                                     f2bf(v.z - bf2f(h2)), f2bf(v.w - bf2f(h3)));
}

// h0 = hidden_state @ W_in + b_in -> h' slices; c0 = 0
__global__ __launch_bounds__(256)
void h0_kernel(const float* __restrict__ hs, const float* __restrict__ W_in,
               const float* __restrict__ b_in, u16* __restrict__ hp,
               float* __restrict__ c)
{
    const int idx = blockIdx.x * 256 + threadIdx.x;
    const int b = idx >> 9, j = idx & 511;
    float acc = b_in[j];
#pragma unroll
    for (int e = 0; e < META_; ++e)
        acc = fmaf(hs[b * META_ + e], W_in[e * H_ + j], acc);
    const u16 hh = f2bf(acc);
    const u16 hl = f2bf(acc - bf2f(hh));
    u16* row = hp + (size_t)b * KT_;
    row[j] = hh; row[512 + j] = hl; row[1024 + j] = hh;
    c[idx] = 0.f;
}

__global__ __launch_bounds__(256)
void init_outputs(float* __restrict__ out, int* __restrict__ tok,
                  int* __restrict__ sl, float* __restrict__ ents)
{
    const int tid = blockIdx.x * 256 + threadIdx.x;
    {
        const int b = tid >> 10;
        const int q = tid & 1023;
        float4 z = make_float4(0.f, 0.f, 0.f, 0.f);
        if (q == 0) z.x = 1.0f;           // SOS = 0
        ((float4*)out)[(size_t)b * ((L_ + 1) * V_ / 4) + q] = z;
    }
    for (size_t t = tid; t < (size_t)B_ * V_; t += (size_t)gridDim.x * 256)
        out[OUT_SP + t] = 0.f;
    if (tid < B_) { tok[tid] = 0; sl[tid] = INIT_LEN_; ents[tid] = 0.f; }
}

// LSTM pointwise: gates = G + E2G[tok]; writes h' slices, embeds output
__global__ __launch_bounds__(256)
void lstm_cell(const float* __restrict__ G, const float* __restrict__ e2g,
               u16* __restrict__ hp, float* __restrict__ c,
               const float* __restrict__ embedding, const int* __restrict__ tok,
               float* __restrict__ out, int step)
{
    const int idx = blockIdx.x * 256 + threadIdx.x;   // B*H
    const int b = idx >> 9, j = idx & 511;
    const size_t g0 = (size_t)b * H4_;
    const size_t e0 = (size_t)tok[b] * H4_;
    const float ig = G[g0 + j]          + e2g[e0 + j];
    const float fg = G[g0 + H_ + j]     + e2g[e0 + H_ + j];
    const float gg = G[g0 + 2 * H_ + j] + e2g[e0 + 2 * H_ + j];
    const float og = G[g0 + 3 * H_ + j] + e2g[e0 + 3 * H_ + j];
    const float si = 1.f / (1.f + expf(-ig));
    const float sf = 1.f / (1.f + expf(-fg));
    const float so = 1.f / (1.f + expf(-og));
    const float cn = sf * c[idx] + si * tanhf(gg);
    c[idx] = cn;
    const float hv = so * tanhf(cn);
    const u16 hh = f2bf(hv);
    const u16 hl = f2bf(hv - bf2f(hh));
    u16* row = hp + (size_t)b * KT_;
    row[j] = hh; row[512 + j] = hl; row[1024 + j] = hh;
    if (j < E_)
        out[OUT_EMB + ((size_t)b * L_ + step) * E_ + j] =
            embedding[(size_t)tok[b] * E_ + j];
}

// per-row: entropy (LSE), argmax(logits+gumbel), one-hot write, state update
__global__ __launch_bounds__(256)
void softmax_step(const float* __restrict__ logits, const float* __restrict__ gumbel,
                  float* __restrict__ out, int* __restrict__ tok,
                  int* __restrict__ sl, float* __restrict__ ents, int step)
{
    const int b   = blockIdx.x;
    const int tid = threadIdx.x;
    const float* lrow = logits + (size_t)b * V_;
    const float* grow = gumbel + ((size_t)step * B_ + b) * V_;
    __shared__ float lsm[V_];
    __shared__ float red_m[4], red_bv[4], red_s[4], red_t[4];
    __shared__ int   red_bi[4];
    __shared__ float s_M;
    __shared__ int   s_bi;

    float m = -3.4e38f, bv = -3.4e38f;
    int bi = 0x7fffffff;
    for (int q = tid; q < V_ / 4; q += 256) {
        float4 l4 = ((const float4*)lrow)[q];
        float4 g4 = ((const float4*)grow)[q];
        ((float4*)lsm)[q] = l4;
        m = fmaxf(m, fmaxf(fmaxf(l4.x, l4.y), fmaxf(l4.z, l4.w)));
        float p; const int i4 = q * 4;
        p = l4.x + g4.x; if (p > bv) { bv = p; bi = i4; }
        p = l4.y + g4.y; if (p > bv) { bv = p; bi = i4 + 1; }
        p = l4.z + g4.z; if (p > bv) { bv = p; bi = i4 + 2; }
        p = l4.w + g4.w; if (p > bv) { bv = p; bi = i4 + 3; }
    }
#pragma unroll
    for (int off = 32; off > 0; off >>= 1) {
        m = fmaxf(m, __shfl_down(m, off));
        float obv = __shfl_down(bv, off);
        int   obi = __shfl_down(bi, off);
        if (obv > bv || (obv == bv && obi < bi)) { bv = obv; bi = obi; }
    }
    const int wave = tid >> 6, lane = tid & 63;
    if (lane == 0) { red_m[wave] = m; red_bv[wave] = bv; red_bi[wave] = bi; }
    __syncthreads();
    if (tid == 0) {
        m = red_m[0]; bv = red_bv[0]; bi = red_bi[0];
        for (int w = 1; w < 4; ++w) {
            m = fmaxf(m, red_m[w]);
            if (red_bv[w] > bv || (red_bv[w] == bv && red_bi[w] < bi)) {
                bv = red_bv[w]; bi = red_bi[w];
            }
        }
        s_M = m; s_bi = bi;
    }
    __syncthreads();
    const float M = s_M;
    const int amax = s_bi;

    float s = 0.f, t = 0.f;
    for (int q = tid; q < V_; q += 256) {
        const float l = lsm[q];
        const float e = __expf(l - M);
        s += e; t += e * l;
    }
#pragma unroll
    for (int off = 32; off > 0; off >>= 1) {
        s += __shfl_down(s, off);
        t += __shfl_down(t, off);
    }
    if (lane == 0) { red_s[wave] = s; red_t[wave] = t; }

    float* orow = out + ((size_t)b * (L_ + 1) + step + 1) * V_;
    const float4 z4 = make_float4(0.f, 0.f, 0.f, 0.f);
    for (int q = tid; q < V_ / 4; q += 256) ((float4*)orow)[q] = z4;
    __syncthreads();
    if (tid == 0) {
        const float ss = red_s[0] + red_s[1] + red_s[2] + red_s[3];
        const float tt = red_t[0] + red_t[1] + red_t[2] + red_t[3];
        const float ent = (M + logf(ss)) - tt / ss;
        ents[b] += ent;
        orow[amax] = 1.0f;
        tok[b] = amax;
        if (amax == EOS_ && sl[b] == INIT_LEN_) sl[b] = step + 2;
    }
}

__global__ __launch_bounds__(256)
void finalize(const int* __restrict__ sl, const float* __restrict__ ents,
              float* __restrict__ out)
{
    const int tid = threadIdx.x;
    float s = 0.f;
    for (int b = tid; b < B_; b += 256) {
        s += ents[b];
        out[OUT_SL + b] = (float)sl[b];
    }
    __shared__ float red[4];
#pragma unroll
    for (int off = 32; off > 0; off >>= 1) s += __shfl_down(s, off);
    if ((tid & 63) == 0) red[tid >> 6] = s;
    __syncthreads();
    if (tid == 0)
        out[OUT_ENT] = (red[0] + red[1] + red[2] + red[3]) / (float)B_ / (float)L_;
}

// ---------------------------------------------------------------------------
extern "C" void kernel_launch(void* const* d_in, const int* in_sizes, int n_in,
                              void* d_out, int out_size, void* d_ws, size_t ws_size,
                              hipStream_t stream)
{
    const float* hidden    = (const float*)d_in[0];
    const float* W_in      = (const float*)d_in[1];
    const float* b_in      = (const float*)d_in[2];
    const float* embedding = (const float*)d_in[3];
    const float* W_ih      = (const float*)d_in[4];
    const float* W_hh      = (const float*)d_in[5];
    const float* b_ih      = (const float*)d_in[6];
    const float* b_hh      = (const float*)d_in[7];
    const float* W_out     = (const float*)d_in[8];
    const float* b_out     = (const float*)d_in[9];
    const float* gumbel    = (const float*)d_in[10];
    float* out = (float*)d_out;

    float* ws    = (float*)d_ws;
    float* E2G   = ws + WS_E2G;
    float* logit = ws + WS_LOGITS;
    float* G     = ws + WS_G;
    float* c     = ws + WS_C;
    u16*   wsu   = (u16*)(ws + WS_F32_END);
    u16* B6      = wsu + U_B6;
    u16* hp      = wsu + U_HP;
    int* tok     = (int*)(wsu + U_END);
    int* sl      = tok + B_;
    float* ents  = (float*)(sl + B_);
    // emb/wih bf16 splits overlay the LOGITS region (dead after E2G build)
    u16* emb_hi  = (u16*)logit;
    u16* emb_lo  = emb_hi + (size_t)V_ * E_;
    u16* wih_hi  = emb_lo + (size_t)V_ * E_;
    u16* wih_lo  = wih_hi + (size_t)H4_ * E_;

    // ---- one-time per call ----
    repack_whh<<<dim3(H4_ / 32, H_ / 64), 256, 0, stream>>>(W_hh, B6);
    repack_wout<<<dim3(V_ / 32, H_ / 64), 256, 0, stream>>>(W_out, B6);
    split_mat<<<(V_ * E_ / 4) / 256, 256, 0, stream>>>(embedding, emb_hi, emb_lo);
    split_mat<<<(H4_ * E_ / 4) / 256, 256, 0, stream>>>(W_ih, wih_hi, wih_lo);
    h0_kernel<<<(B_ * H_) / 256, 256, 0, stream>>>(hidden, W_in, b_in, hp, c);
    init_outputs<<<(B_ * V_ / 4) / 256, 256, 0, stream>>>(out, tok, sl, ents);
    // E2G = embedding @ W_ih^T + b_ih + b_hh   [V, 4H]  (old kernel, once)
    gemm3<0><<<dim3(H4_ / 128, V_ / 128), 256, 0, stream>>>(
        emb_hi, emb_lo, wih_hi, wih_lo, E2G, nullptr, E_, b_ih, b_hh, 0);
    // G0 = h0 @ W_hh^T  (panels 0-7 only)
    gemm8<<<dim3(8, 8), 512, 0, stream>>>(hp, B6, G, logit, b_out, 0);

    for (int i = 0; i < L_; ++i) {
        lstm_cell<<<(B_ * H_) / 256, 256, 0, stream>>>(G, E2G, hp, c,
                                                       embedding, tok, out, i);
        if (i < L_ - 1) {
            // [G_{i+1} | logits_i] = h_{i+1} @ [W_hh | WoutT]^T  (24 panels)
            gemm8<<<dim3(24, 8), 512, 0, stream>>>(hp, B6, G, logit, b_out, 0);
        } else {
            // logits only (panels 8-23)
            gemm8<<<dim3(16, 8), 512, 0, stream>>>(hp, B6, G, logit, b_out, 8);
        }
        softmax_step<<<B_, 256, 0, stream>>>(logit, gumbel, out, tok, sl, ents, i);
    }
    finalize<<<1, 256, 0, stream>>>(sl, ents, out);
}

// Round 5
// 1034.560 us; speedup vs baseline: 1.1810x; 1.1810x over previous
//
#include <hip/hip_runtime.h>
#include <hip/hip_bf16.h>
#include <math.h>

typedef unsigned short u16;
typedef __attribute__((ext_vector_type(8))) short bf16x8;
typedef __attribute__((ext_vector_type(4))) float f32x4;

#define B_    2048
#define V_    4096
#define L_    10
#define H_    512
#define E_    256
#define META_ 15
#define H4_   2048
#define KT_   1536                 // tripled K  (hi | lo | hi on A,  hi | hi | lo on B)
#define NT_   48                   // KT_/32 k-tiles
#define EOS_  0
#define INIT_LEN_ (L_ + 1)

// ---- output layout (flat f32, reference return order) ----
constexpr size_t OUT_SL  = (size_t)B_ * (L_ + 1) * V_;
constexpr size_t OUT_ENT = OUT_SL + B_;
constexpr size_t OUT_EMB = OUT_ENT + 1;
constexpr size_t OUT_SP  = OUT_EMB + (size_t)B_ * L_ * E_;

// ---- workspace layout ----
constexpr size_t WS_E2G     = 0;                              // [V,4H] f32
constexpr size_t WS_LOGITS  = WS_E2G    + (size_t)V_ * H4_;   // [B,V] f32
constexpr size_t WS_G       = WS_LOGITS + (size_t)B_ * V_;    // [B,4H] f32
constexpr size_t WS_C       = WS_G      + (size_t)B_ * H4_;   // [B,H] f32
constexpr size_t WS_F32_END = WS_C      + (size_t)B_ * H_;
constexpr size_t U_B6       = 0;                              // [24 panels][48 kt][8192] u16
constexpr size_t U_HP       = U_B6 + (size_t)6144 * KT_;      // [8 panels][48 kt][8192] u16
constexpr size_t U_END      = U_HP + (size_t)B_ * KT_;

__device__ __forceinline__ u16 f2bf(float f) {
    union { __hip_bfloat16 b; u16 u; } cv; cv.b = __float2bfloat16(f); return cv.u;
}
__device__ __forceinline__ float bf2f(u16 u) {
    union { u16 u; __hip_bfloat16 b; } cv; cv.u = u; return __bfloat162float(cv.b);
}
__device__ __forceinline__ void gld16(const u16* g, void* l) {
    __builtin_amdgcn_global_load_lds(
        (const __attribute__((address_space(1))) unsigned int*)g,
        (__attribute__((address_space(3))) unsigned int*)l, 16, 0, 0);
}

// tile-linear packed addressing (both A and B): 256-row panels, 32-k tiles,
// within tile: [s = (k>>3)&3][row][e = k&7]  (8192 elems / tile)
__device__ __forceinline__ size_t pk_addr(int row256, int k) {
    return (size_t)(k >> 5) * 8192 + (size_t)((k >> 3) & 3) * 2048 +
           (size_t)row256 * 8 + (k & 7);
}
__device__ __forceinline__ size_t b6_addr(int col, int k) {
    return (size_t)(col >> 8) * (NT_ * 8192) + pk_addr(col & 255, k);
}
__device__ __forceinline__ size_t a6_addr(int b, int k) {
    return (size_t)(b >> 8) * (NT_ * 8192) + pk_addr(b & 255, k);
}

// ---------------------------------------------------------------------------
// Pipelined 256x256 bf16 NT GEMM over K=1536, BK=32, 3 LDS buffers, depth-2
// counted-vmcnt prefetch, 1 barrier/tile.  8 waves (2M x 4N).
// col panels < 8 -> G (ldc=4H, raw); panels >= 8 -> LOGITS (ldc=V) + bias.
// ---------------------------------------------------------------------------
__global__ __launch_bounds__(512, 1)
void gemmP(const u16* __restrict__ A6, const u16* __restrict__ B6,
           float* __restrict__ G, float* __restrict__ LOG,
           const float* __restrict__ bias, int xoff)
{
    __shared__ u16 As[3][8192];
    __shared__ u16 Bs[3][8192];
    const int tid  = threadIdx.x;
    const int lane = tid & 63;
    const int wave = tid >> 6;
    const int wr = wave >> 2, wc = wave & 3;      // 2M x 4N
    const int fr = lane & 15, kq = lane >> 4;

    // bijective XCD-chunked swizzle (gridDim.y == 8)
    const int nwg = gridDim.x * gridDim.y;
    const int bid = blockIdx.y * gridDim.x + blockIdx.x;
    const int w   = (bid & 7) * (nwg >> 3) + (bid >> 3);
    const int colb = (w >> 3) + xoff;
    const int row0 = (w & 7) * 256;
    const int col0 = colb * 256;

    const u16* Asrc = A6 + (size_t)(w & 7) * (NT_ * 8192) + tid * 8;
    const u16* Bsrc = B6 + (size_t)colb * (NT_ * 8192) + tid * 8;
    const int dst0 = tid * 8;

    // fragment element bases within a tile
    const int abase = kq * 2048 + (wr * 128 + fr) * 8;   // + m*128
    const int bbase = kq * 2048 + (wc * 64 + fr) * 8;    // + n*128

    f32x4 acc[8][4] = {};

#define STAGE(buf, kt) do {                                   \
    const u16* as_ = Asrc + (size_t)(kt) * 8192;              \
    const u16* bs_ = Bsrc + (size_t)(kt) * 8192;              \
    gld16(as_,        &As[buf][dst0]);                        \
    gld16(as_ + 4096, &As[buf][dst0 + 4096]);                 \
    gld16(bs_,        &Bs[buf][dst0]);                        \
    gld16(bs_ + 4096, &Bs[buf][dst0 + 4096]);                 \
  } while (0)

#define TILE(T, CBUF, SBUF) do {                                              \
    if ((T) == NT_ - 1) asm volatile("s_waitcnt vmcnt(0)" ::: "memory");      \
    else                asm volatile("s_waitcnt vmcnt(4)" ::: "memory");      \
    __builtin_amdgcn_s_barrier();                                             \
    const u16* ab = &As[CBUF][abase];                                         \
    const u16* bb = &Bs[CBUF][bbase];                                         \
    bf16x8 bv[4], av[4];                                                      \
    _Pragma("unroll")                                                         \
    for (int n = 0; n < 4; ++n) bv[n] = *(const bf16x8*)(bb + n * 128);       \
    _Pragma("unroll")                                                         \
    for (int m = 0; m < 4; ++m) av[m] = *(const bf16x8*)(ab + m * 128);       \
    if ((T) < NT_ - 2) STAGE(SBUF, (T) + 2);                                  \
    __builtin_amdgcn_s_setprio(1);                                            \
    _Pragma("unroll")                                                         \
    for (int m = 0; m < 4; ++m)                                               \
      _Pragma("unroll")                                                       \
      for (int n = 0; n < 4; ++n)                                             \
        acc[m][n] = __builtin_amdgcn_mfma_f32_16x16x32_bf16(av[m], bv[n], acc[m][n], 0, 0, 0); \
    __builtin_amdgcn_s_setprio(0);                                            \
    bf16x8 av2[4];                                                            \
    _Pragma("unroll")                                                         \
    for (int m = 0; m < 4; ++m) av2[m] = *(const bf16x8*)(ab + (4 + m) * 128);\
    __builtin_amdgcn_s_setprio(1);                                            \
    _Pragma("unroll")                                                         \
    for (int m = 0; m < 4; ++m)                                               \
      _Pragma("unroll")                                                       \
      for (int n = 0; n < 4; ++n)                                             \
        acc[4 + m][n] = __builtin_amdgcn_mfma_f32_16x16x32_bf16(av2[m], bv[n], acc[4 + m][n], 0, 0, 0); \
    __builtin_amdgcn_s_setprio(0);                                            \
  } while (0)

    STAGE(0, 0);
    STAGE(1, 1);
    for (int tt = 0; tt < NT_; tt += 3) {
        TILE(tt,     0, 2);
        TILE(tt + 1, 1, 0);
        TILE(tt + 2, 2, 1);
    }
#undef TILE
#undef STAGE

    // epilogue
    const bool isG = (col0 < H4_);
    float* Cb      = isG ? G : LOG;
    const int ldc  = isG ? H4_ : V_;
    const int cbase = (isG ? col0 : col0 - H4_) + wc * 64 + fr;
#pragma unroll
    for (int m = 0; m < 8; ++m) {
#pragma unroll
        for (int r = 0; r < 4; ++r) {
            const int grow = row0 + wr * 128 + m * 16 + kq * 4 + r;
            float* cp = Cb + (size_t)grow * ldc + cbase;
#pragma unroll
            for (int n = 0; n < 4; ++n) {
                float v = acc[m][n][r];
                if (!isG) v += bias[cbase + n * 16];
                cp[n * 16] = v;
            }
        }
    }
}

// ---------------------------------------------------------------------------
// repack W_hh [2048][512] f32 -> B6 panels 0-7 (hi|hi|lo over K)
__global__ __launch_bounds__(256)
void repack_whh(const float* __restrict__ W_hh, u16* __restrict__ B6)
{
    const int c0 = blockIdx.x * 32, k0 = blockIdx.y * 64;
    const int cc = threadIdx.x & 31, kg = threadIdx.x >> 5;
    const int col = c0 + cc;
#pragma unroll
    for (int e = 0; e < 8; ++e) {
        const int kp = k0 + kg * 8 + e;               // 0..511
        const float v = W_hh[(size_t)col * H_ + kp];
        const u16 h = f2bf(v);
        const u16 l = f2bf(v - bf2f(h));
        B6[b6_addr(col, kp)]          = h;
        B6[b6_addr(col, 512 + kp)]    = h;
        B6[b6_addr(col, 1024 + kp)]   = l;
    }
}

// repack W_out [512][4096] f32 (transposed) -> B6 panels 8-23
__global__ __launch_bounds__(256)
void repack_wout(const float* __restrict__ W_out, u16* __restrict__ B6)
{
    __shared__ float t[64][33];
    const int c0 = blockIdx.x * 32, k0 = blockIdx.y * 64;
    const int x = threadIdx.x & 31, y = threadIdx.x >> 5;   // 32 x 8
    for (int yy = y; yy < 64; yy += 8)
        t[yy][x] = W_out[(size_t)(k0 + yy) * V_ + c0 + x];
    __syncthreads();
    const int cc = threadIdx.x & 31, kg = threadIdx.x >> 5;
    const int col = 2048 + c0 + cc;
#pragma unroll
    for (int e = 0; e < 8; ++e) {
        const int kp = k0 + kg * 8 + e;
        const float v = t[kp - k0][cc];
        const u16 h = f2bf(v);
        const u16 l = f2bf(v - bf2f(h));
        B6[b6_addr(col, kp)]        = h;
        B6[b6_addr(col, 512 + kp)]  = h;
        B6[b6_addr(col, 1024 + kp)] = l;
    }
}

// ---------------------------------------------------------------------------
// old-style 128^2 MFMA GEMM kept for the one-time E2G build
__global__ __launch_bounds__(256)
void gemm_e2g(const u16* __restrict__ Ah, const u16* __restrict__ Al,
              const u16* __restrict__ Bh, const u16* __restrict__ Bl,
              float* __restrict__ C0, int K,
              const float* __restrict__ bias0, const float* __restrict__ bias1)
{
    __shared__ u16 As[2][128][32];
    __shared__ u16 Bs[2][128][32];
    const int tid  = threadIdx.x;
    const int lane = tid & 63;
    const int wave = tid >> 6;
    const int wm = wave >> 1, wn = wave & 1;
    const int nwg  = gridDim.x * gridDim.y;
    const int bid  = blockIdx.y * gridDim.x + blockIdx.x;
    const int w    = (bid & 7) * (nwg >> 3) + (bid >> 3);
    const int colb = w / gridDim.y;
    const int rowb = w % gridDim.y;
    const int col0 = colb * 128;
    const int row0 = rowb * 128;

    const int srow = tid >> 2;
    const int scol = (tid & 3) * 8;
    const size_t aoff = (size_t)(row0 + srow) * K + scol;
    const size_t boff = (size_t)(col0 + srow) * K + scol;
    const size_t skip = (size_t)64 * K;

    u16* lA0 = &As[0][0][0];
    u16* lA1 = &As[1][0][0];
    u16* lB0 = &Bs[0][0][0];
    u16* lB1 = &Bs[1][0][0];
    const int d0 = tid * 8;
    const int d1 = d0 + 2048;

    f32x4 acc[4][4] = {};
    const int fr = lane & 15;
    const int kq = lane >> 4;

    for (int k0 = 0; k0 < K; k0 += 32) {
        __syncthreads();
        gld16(Ah + aoff + k0,        lA0 + d0);
        gld16(Ah + aoff + k0 + skip, lA0 + d1);
        gld16(Al + aoff + k0,        lA1 + d0);
        gld16(Al + aoff + k0 + skip, lA1 + d1);
        gld16(Bh + boff + k0,        lB0 + d0);
        gld16(Bh + boff + k0 + skip, lB0 + d1);
        gld16(Bl + boff + k0,        lB1 + d0);
        gld16(Bl + boff + k0 + skip, lB1 + d1);
        __syncthreads();

        bf16x8 ah[4], al[4], bh[4], bl[4];
#pragma unroll
        for (int i = 0; i < 4; ++i) {
            ah[i] = *(const bf16x8*)&As[0][wm * 64 + i * 16 + fr][kq * 8];
            al[i] = *(const bf16x8*)&As[1][wm * 64 + i * 16 + fr][kq * 8];
            bh[i] = *(const bf16x8*)&Bs[0][wn * 64 + i * 16 + fr][kq * 8];
            bl[i] = *(const bf16x8*)&Bs[1][wn * 64 + i * 16 + fr][kq * 8];
        }
#pragma unroll
        for (int mi = 0; mi < 4; ++mi)
#pragma unroll
            for (int ni = 0; ni < 4; ++ni) {
                acc[mi][ni] = __builtin_amdgcn_mfma_f32_16x16x32_bf16(ah[mi], bh[ni], acc[mi][ni], 0, 0, 0);
                acc[mi][ni] = __builtin_amdgcn_mfma_f32_16x16x32_bf16(ah[mi], bl[ni], acc[mi][ni], 0, 0, 0);
                acc[mi][ni] = __builtin_amdgcn_mfma_f32_16x16x32_bf16(al[mi], bh[ni], acc[mi][ni], 0, 0, 0);
            }
    }

    const int cc0 = col0 + wn * 64 + fr;
#pragma unroll
    for (int mi = 0; mi < 4; ++mi) {
#pragma unroll
        for (int r = 0; r < 4; ++r) {
            const int grow = row0 + wm * 64 + mi * 16 + kq * 4 + r;
            float* cp = C0 + (size_t)grow * H4_ + cc0;
#pragma unroll
            for (int ni = 0; ni < 4; ++ni)
                cp[ni * 16] = acc[mi][ni][r] + bias0[cc0 + ni * 16] + bias1[cc0 + ni * 16];
        }
    }
}

// ---------------------------------------------------------------------------
// elementwise f32 -> bf16 hi/lo split (emb, W_ih for E2G build)
__global__ __launch_bounds__(256)
void split_mat(const float* __restrict__ X, u16* __restrict__ hi,
               u16* __restrict__ lo)
{
    const int i = blockIdx.x * 256 + threadIdx.x;
    float4 v = ((const float4*)X)[i];
    const u16 h0 = f2bf(v.x), h1 = f2bf(v.y), h2 = f2bf(v.z), h3 = f2bf(v.w);
    ((ushort4*)hi)[i] = make_ushort4(h0, h1, h2, h3);
    ((ushort4*)lo)[i] = make_ushort4(f2bf(v.x - bf2f(h0)), f2bf(v.y - bf2f(h1)),
                                     f2bf(v.z - bf2f(h2)), f2bf(v.w - bf2f(h3)));
}

// h0 = hidden_state @ W_in + b_in -> packed A6 slices; c0 = 0
__global__ __launch_bounds__(256)
void h0_kernel(const float* __restrict__ hs, const float* __restrict__ W_in,
               const float* __restrict__ b_in, u16* __restrict__ hp,
               float* __restrict__ c)
{
    const int idx = blockIdx.x * 256 + threadIdx.x;
    const int b = idx >> 9, j = idx & 511;
    float acc = b_in[j];
#pragma unroll
    for (int e = 0; e < META_; ++e)
        acc = fmaf(hs[b * META_ + e], W_in[e * H_ + j], acc);
    const u16 hh = f2bf(acc);
    const u16 hl = f2bf(acc - bf2f(hh));
    hp[a6_addr(b, j)]        = hh;
    hp[a6_addr(b, 512 + j)]  = hl;
    hp[a6_addr(b, 1024 + j)] = hh;
    c[idx] = 0.f;
}

__global__ __launch_bounds__(256)
void init_outputs(float* __restrict__ out, int* __restrict__ tok,
                  int* __restrict__ sl, float* __restrict__ ents)
{
    const int tid = blockIdx.x * 256 + threadIdx.x;
    {
        const int b = tid >> 10;
        const int q = tid & 1023;
        float4 z = make_float4(0.f, 0.f, 0.f, 0.f);
        if (q == 0) z.x = 1.0f;           // SOS = 0
        ((float4*)out)[(size_t)b * ((L_ + 1) * V_ / 4) + q] = z;
    }
    for (size_t t = tid; t < (size_t)B_ * V_; t += (size_t)gridDim.x * 256)
        out[OUT_SP + t] = 0.f;
    if (tid < B_) { tok[tid] = 0; sl[tid] = INIT_LEN_; ents[tid] = 0.f; }
}

// LSTM pointwise: gates = G + E2G[tok]; writes packed A6 h-slices, embeds out
__global__ __launch_bounds__(256)
void lstm_cell(const float* __restrict__ G, const float* __restrict__ e2g,
               u16* __restrict__ hp, float* __restrict__ c,
               const float* __restrict__ embedding, const int* __restrict__ tok,
               float* __restrict__ out, int step)
{
    const int idx = blockIdx.x * 256 + threadIdx.x;   // B*H
    const int b = idx >> 9, j = idx & 511;
    const size_t g0 = (size_t)b * H4_;
    const size_t e0 = (size_t)tok[b] * H4_;
    const float ig = G[g0 + j]          + e2g[e0 + j];
    const float fg = G[g0 + H_ + j]     + e2g[e0 + H_ + j];
    const float gg = G[g0 + 2 * H_ + j] + e2g[e0 + 2 * H_ + j];
    const float og = G[g0 + 3 * H_ + j] + e2g[e0 + 3 * H_ + j];
    const float si = 1.f / (1.f + expf(-ig));
    const float sf = 1.f / (1.f + expf(-fg));
    const float so = 1.f / (1.f + expf(-og));
    const float cn = sf * c[idx] + si * tanhf(gg);
    c[idx] = cn;
    const float hv = so * tanhf(cn);
    const u16 hh = f2bf(hv);
    const u16 hl = f2bf(hv - bf2f(hh));
    hp[a6_addr(b, j)]        = hh;
    hp[a6_addr(b, 512 + j)]  = hl;
    hp[a6_addr(b, 1024 + j)] = hh;
    if (j < E_)
        out[OUT_EMB + ((size_t)b * L_ + step) * E_ + j] =
            embedding[(size_t)tok[b] * E_ + j];
}

// per-row: entropy (LSE), argmax(logits+gumbel), one-hot write, state update
__global__ __launch_bounds__(256)
void softmax_step(const float* __restrict__ logits, const float* __restrict__ gumbel,
                  float* __restrict__ out, int* __restrict__ tok,
                  int* __restrict__ sl, float* __restrict__ ents, int step)
{
    const int b   = blockIdx.x;
    const int tid = threadIdx.x;
    const float* lrow = logits + (size_t)b * V_;
    const float* grow = gumbel + ((size_t)step * B_ + b) * V_;
    __shared__ float lsm[V_];
    __shared__ float red_m[4], red_bv[4], red_s[4], red_t[4];
    __shared__ int   red_bi[4];
    __shared__ float s_M;
    __shared__ int   s_bi;

    float m = -3.4e38f, bv = -3.4e38f;
    int bi = 0x7fffffff;
    for (int q = tid; q < V_ / 4; q += 256) {
        float4 l4 = ((const float4*)lrow)[q];
        float4 g4 = ((const float4*)grow)[q];
        ((float4*)lsm)[q] = l4;
        m = fmaxf(m, fmaxf(fmaxf(l4.x, l4.y), fmaxf(l4.z, l4.w)));
        float p; const int i4 = q * 4;
        p = l4.x + g4.x; if (p > bv) { bv = p; bi = i4; }
        p = l4.y + g4.y; if (p > bv) { bv = p; bi = i4 + 1; }
        p = l4.z + g4.z; if (p > bv) { bv = p; bi = i4 + 2; }
        p = l4.w + g4.w; if (p > bv) { bv = p; bi = i4 + 3; }
    }
#pragma unroll
    for (int off = 32; off > 0; off >>= 1) {
        m = fmaxf(m, __shfl_down(m, off));
        float obv = __shfl_down(bv, off);
        int   obi = __shfl_down(bi, off);
        if (obv > bv || (obv == bv && obi < bi)) { bv = obv; bi = obi; }
    }
    const int wave = tid >> 6, lane = tid & 63;
    if (lane == 0) { red_m[wave] = m; red_bv[wave] = bv; red_bi[wave] = bi; }
    __syncthreads();
    if (tid == 0) {
        m = red_m[0]; bv = red_bv[0]; bi = red_bi[0];
        for (int w = 1; w < 4; ++w) {
            m = fmaxf(m, red_m[w]);
            if (red_bv[w] > bv || (red_bv[w] == bv && red_bi[w] < bi)) {
                bv = red_bv[w]; bi = red_bi[w];
            }
        }
        s_M = m; s_bi = bi;
    }
    __syncthreads();
    const float M = s_M;
    const int amax = s_bi;

    float s = 0.f, t = 0.f;
    for (int q = tid; q < V_; q += 256) {
        const float l = lsm[q];
        const float e = __expf(l - M);
        s += e; t += e * l;
    }
#pragma unroll
    for (int off = 32; off > 0; off >>= 1) {
        s += __shfl_down(s, off);
        t += __shfl_down(t, off);
    }
    if (lane == 0) { red_s[wave] = s; red_t[wave] = t; }

    float* orow = out + ((size_t)b * (L_ + 1) + step + 1) * V_;
    const float4 z4 = make_float4(0.f, 0.f, 0.f, 0.f);
    for (int q = tid; q < V_ / 4; q += 256) ((float4*)orow)[q] = z4;
    __syncthreads();
    if (tid == 0) {
        const float ss = red_s[0] + red_s[1] + red_s[2] + red_s[3];
        const float tt = red_t[0] + red_t[1] + red_t[2] + red_t[3];
        const float ent = (M + logf(ss)) - tt / ss;
        ents[b] += ent;
        orow[amax] = 1.0f;
        tok[b] = amax;
        if (amax == EOS_ && sl[b] == INIT_LEN_) sl[b] = step + 2;
    }
}

__global__ __launch_bounds__(256)
void finalize(const int* __restrict__ sl, const float* __restrict__ ents,
              float* __restrict__ out)
{
    const int tid = threadIdx.x;
    float s = 0.f;
    for (int b = tid; b < B_; b += 256) {
        s += ents[b];
        out[OUT_SL + b] = (float)sl[b];
    }
    __shared__ float red[4];
#pragma unroll
    for (int off = 32; off > 0; off >>= 1) s += __shfl_down(s, off);
    if ((tid & 63) == 0) red[tid >> 6] = s;
    __syncthreads();
    if (tid == 0)
        out[OUT_ENT] = (red[0] + red[1] + red[2] + red[3]) / (float)B_ / (float)L_;
}

// ---------------------------------------------------------------------------
extern "C" void kernel_launch(void* const* d_in, const int* in_sizes, int n_in,
                              void* d_out, int out_size, void* d_ws, size_t ws_size,
                              hipStream_t stream)
{
    const float* hidden    = (const float*)d_in[0];
    const float* W_in      = (const float*)d_in[1];
    const float* b_in      = (const float*)d_in[2];
    const float* embedding = (const float*)d_in[3];
    const float* W_ih      = (const float*)d_in[4];
    const float* W_hh      = (const float*)d_in[5];
    const float* b_ih      = (const float*)d_in[6];
    const float* b_hh      = (const float*)d_in[7];
    const float* W_out     = (const float*)d_in[8];
    const float* b_out     = (const float*)d_in[9];
    const float* gumbel    = (const float*)d_in[10];
    float* out = (float*)d_out;

    float* ws    = (float*)d_ws;
    float* E2G   = ws + WS_E2G;
    float* logit = ws + WS_LOGITS;
    float* G     = ws + WS_G;
    float* c     = ws + WS_C;
    u16*   wsu   = (u16*)(ws + WS_F32_END);
    u16* B6      = wsu + U_B6;
    u16* hp      = wsu + U_HP;
    int* tok     = (int*)(wsu + U_END);
    int* sl      = tok + B_;
    float* ents  = (float*)(sl + B_);
    // emb/wih bf16 splits overlay the LOGITS region (dead after E2G build)
    u16* emb_hi  = (u16*)logit;
    u16* emb_lo  = emb_hi + (size_t)V_ * E_;
    u16* wih_hi  = emb_lo + (size_t)V_ * E_;
    u16* wih_lo  = wih_hi + (size_t)H4_ * E_;

    // ---- one-time per call ----
    repack_whh<<<dim3(H4_ / 32, H_ / 64), 256, 0, stream>>>(W_hh, B6);
    repack_wout<<<dim3(V_ / 32, H_ / 64), 256, 0, stream>>>(W_out, B6);
    split_mat<<<(V_ * E_ / 4) / 256, 256, 0, stream>>>(embedding, emb_hi, emb_lo);
    split_mat<<<(H4_ * E_ / 4) / 256, 256, 0, stream>>>(W_ih, wih_hi, wih_lo);
    h0_kernel<<<(B_ * H_) / 256, 256, 0, stream>>>(hidden, W_in, b_in, hp, c);
    init_outputs<<<(B_ * V_ / 4) / 256, 256, 0, stream>>>(out, tok, sl, ents);
    // E2G = embedding @ W_ih^T + b_ih + b_hh   [V, 4H]
    gemm_e2g<<<dim3(H4_ / 128, V_ / 128), 256, 0, stream>>>(
        emb_hi, emb_lo, wih_hi, wih_lo, E2G, E_, b_ih, b_hh);
    // G0 = h0 @ W_hh^T  (panels 0-7 only)
    gemmP<<<dim3(8, 8), 512, 0, stream>>>(hp, B6, G, logit, b_out, 0);

    for (int i = 0; i < L_; ++i) {
        lstm_cell<<<(B_ * H_) / 256, 256, 0, stream>>>(G, E2G, hp, c,
                                                       embedding, tok, out, i);
        if (i < L_ - 1) {
            // [G_{i+1} | logits_i] = h_{i+1} @ [W_hh | WoutT]^T  (24 panels)
            gemmP<<<dim3(24, 8), 512, 0, stream>>>(hp, B6, G, logit, b_out, 0);
        } else {
            // logits only (panels 8-23)
            gemmP<<<dim3(16, 8), 512, 0, stream>>>(hp, B6, G, logit, b_out, 8);
        }
        softmax_step<<<B_, 256, 0, stream>>>(logit, gumbel, out, tok, sl, ents, i);
    }
    finalize<<<1, 256, 0, stream>>>(sl, ents, out);
}